// Round 1
// baseline (47.996 us; speedup 1.0000x reference)
//
#include <hip/hip_runtime.h>
#include <math.h>

#define S_LEN 2048
#define B_SZ  32
#define DIM   1024   // D == E == H == 1024
#define PTR   9      // min((0 + 9) * 1, 2047)
#define EPSV  1e-8f
#define NEGINF -1e9f

#define BK 64
#define BM 32
#define BN 32

// ---------------- K0: alpha one-hot ----------------
__global__ void k_alpha(float* __restrict__ alpha) {
    int i = blockIdx.x * blockDim.x + threadIdx.x;
    if (i < S_LEN * B_SZ) {
        int s = i / B_SZ;
        alpha[i] = (s == PTR - 1) ? 1.0f : 0.0f;
    }
}

// ---------------- K1: fused dec+enc GEMM ----------------
// C rows 0..31  = input @ W_dec + b           (dec, per batch b)
// C rows 32..319 = src[s,b,:] @ W_enc, s<9    (enc, row 32 + s*32 + b)
__global__ __launch_bounds__(256) void k_gemm(
    const float* __restrict__ input,
    const float* __restrict__ src,
    const float* __restrict__ Wdec,
    const float* __restrict__ Wenc,
    const float* __restrict__ bias,
    float* __restrict__ C)
{
    __shared__ float As[BM][BK + 4];
    __shared__ float Bs[BK][BN + 4];
    const int t  = blockIdx.y;        // m-tile 0..9
    const int n0 = blockIdx.x * BN;
    const float* A = (t == 0) ? input : (src + (size_t)(t - 1) * B_SZ * DIM);
    const float* W = (t == 0) ? Wdec : Wenc;

    const int tid = threadIdx.x;
    const int tx = tid & 15;          // n-group
    const int ty = tid >> 4;          // m-group
    float acc00 = 0.f, acc01 = 0.f, acc10 = 0.f, acc11 = 0.f;

    for (int k0 = 0; k0 < DIM; k0 += BK) {
        #pragma unroll
        for (int i = 0; i < 2; i++) {          // A tile: 32x64 = 512 float4
            int idx = tid + i * 256;
            int r = idx >> 4, c4 = idx & 15;
            float4 av = *(const float4*)(A + (size_t)r * DIM + k0 + c4 * 4);
            *(float4*)&As[r][c4 * 4] = av;
        }
        #pragma unroll
        for (int i = 0; i < 2; i++) {          // B tile: 64x32 = 512 float4
            int idx = tid + i * 256;
            int r = idx >> 3, c4 = idx & 7;
            float4 bv = *(const float4*)(W + (size_t)(k0 + r) * DIM + n0 + c4 * 4);
            *(float4*)&Bs[r][c4 * 4] = bv;
        }
        __syncthreads();
        #pragma unroll
        for (int kk = 0; kk < BK; kk++) {
            float a0 = As[2 * ty][kk];
            float a1 = As[2 * ty + 1][kk];
            float b0 = Bs[kk][2 * tx];
            float b1 = Bs[kk][2 * tx + 1];
            acc00 += a0 * b0; acc01 += a0 * b1;
            acc10 += a1 * b0; acc11 += a1 * b1;
        }
        __syncthreads();
    }
    const int m0 = 2 * ty, n = n0 + 2 * tx;
    if (t == 0) {
        float bb0 = bias[n], bb1 = bias[n + 1];
        acc00 += bb0; acc01 += bb1; acc10 += bb0; acc11 += bb1;
    }
    float* Crow = C + (size_t)(t * BM + m0) * DIM + n;
    Crow[0] = acc00; Crow[1] = acc01;
    Crow[DIM] = acc10; Crow[DIM + 1] = acc11;
}

// ---------------- K2: energies e[s,b] = v . tanh(enc + dec) ----------------
__global__ __launch_bounds__(256) void k_energy(
    const float* __restrict__ C,
    const unsigned char* __restrict__ mask,   // (S,B) bool
    const float* __restrict__ v,
    float* __restrict__ e)                    // 288
{
    int wave = threadIdx.x >> 6;
    int lane = threadIdx.x & 63;
    int r = blockIdx.x * 4 + wave;            // 0..287
    int b = r & 31;
    const float* enc = C + (size_t)(32 + r) * DIM;
    const float* dec = C + (size_t)b * DIM;
    float sum = 0.f;
    #pragma unroll 4
    for (int h = lane; h < DIM; h += 64)
        sum += v[h] * tanhf(enc[h] + dec[h]);
    #pragma unroll
    for (int off = 32; off; off >>= 1) sum += __shfl_down(sum, off);
    if (lane == 0) {
        int s = r >> 5;
        if (mask[s * B_SZ + b]) sum = NEGINF;
        e[r] = sum;
    }
}

// ---------------- K3: softmax(9) + weighted context ----------------
__global__ __launch_bounds__(256) void k_context(
    const float* __restrict__ e,
    const float* __restrict__ src,
    float* __restrict__ out)                  // 32 x 1024
{
    int b = blockIdx.x;
    float ev[PTR];
    float m = -INFINITY;
    #pragma unroll
    for (int s = 0; s < PTR; s++) { ev[s] = e[s * B_SZ + b]; m = fmaxf(m, ev[s]); }
    float sum = 0.f;
    #pragma unroll
    for (int s = 0; s < PTR; s++) { ev[s] = expf(ev[s] - m) + EPSV; sum += ev[s]; }
    float inv = 1.0f / sum;
    int h = threadIdx.x * 4;
    float4 acc = {0.f, 0.f, 0.f, 0.f};
    #pragma unroll
    for (int s = 0; s < PTR; s++) {
        float w = ev[s] * inv;
        float4 x = *(const float4*)(src + (size_t)(s * B_SZ + b) * DIM + h);
        acc.x += w * x.x; acc.y += w * x.y; acc.z += w * x.z; acc.w += w * x.w;
    }
    *(float4*)(out + (size_t)b * DIM + h) = acc;
}

extern "C" void kernel_launch(void* const* d_in, const int* in_sizes, int n_in,
                              void* d_out, int out_size, void* d_ws, size_t ws_size,
                              hipStream_t stream) {
    const float* input = (const float*)d_in[0];
    const float* src   = (const float*)d_in[1];
    const unsigned char* mask = (const unsigned char*)d_in[2];
    const float* Wdec  = (const float*)d_in[3];
    const float* Wenc  = (const float*)d_in[4];
    const float* bias  = (const float*)d_in[5];
    const float* v     = (const float*)d_in[6];
    float* out   = (float*)d_out;
    float* alpha = out + B_SZ * DIM;

    float* C = (float*)d_ws;                 // 320*1024 floats
    float* e = C + 320 * DIM;                // 288 floats

    k_alpha<<<dim3((S_LEN * B_SZ + 255) / 256), 256, 0, stream>>>(alpha);
    k_gemm<<<dim3(DIM / BN, 10), 256, 0, stream>>>(input, src, Wdec, Wenc, bias, C);
    k_energy<<<dim3(288 / 4), 256, 0, stream>>>(C, mask, v, e);
    k_context<<<dim3(B_SZ), 256, 0, stream>>>(e, src, out);
}

// Round 2
// 29.760 us; speedup vs baseline: 1.6127x; 1.6127x over previous
//
#include <hip/hip_runtime.h>
#include <math.h>

#define S_LEN 2048
#define B_SZ  32
#define DIM   1024   // D == E == H == 1024
#define PTR   9      // min((0 + 9) * 1, 2047)
#define EPSV  1e-8f
#define NEGINF -1e9f

// GEMM tiling
#define BK 32
#define BM 32
#define BN 128
#define ASTR 36      // As row stride (floats), 16B-aligned, breaks pow2
#define BSTR 132     // Bs row stride (floats)
#define MROWS 320    // 32 dec rows + 288 enc rows

__device__ __forceinline__ float fast_tanh(float x) {
    float xc = fminf(fmaxf(x, -20.f), 20.f);
    float t = __expf(2.f * xc);                       // v_exp_f32 path
    return (t - 1.f) * __builtin_amdgcn_rcpf(t + 1.f);
}

// ---------------- K1: fused dec+enc GEMM, split-K partials ----------------
// Cp[kz][row][h]; row 0..31 = dec partial (no bias), row 32+s*32+b = enc partial
__global__ __launch_bounds__(256) void k_gemm(
    const float* __restrict__ input,
    const float* __restrict__ src,
    const float* __restrict__ Wdec,
    const float* __restrict__ Wenc,
    float* __restrict__ Cp,
    int Kslice)
{
    __shared__ float As[BK][ASTR];   // k-major: As[k][m]
    __shared__ float Bs[BK][BSTR];
    const int t  = blockIdx.y;            // 0..9 (0 = dec)
    const int n0 = blockIdx.x * BN;
    const int kz = blockIdx.z;
    const int k_beg = kz * Kslice;
    const int k_end = k_beg + Kslice;
    const float* A = (t == 0) ? input : (src + (size_t)(t - 1) * B_SZ * DIM);
    const float* W = (t == 0) ? Wdec : Wenc;

    const int tid = threadIdx.x;
    const int my = tid & 7;               // m-group (4 rows each)
    const int nx = tid >> 3;              // n-group 0..31 (4 cols each)
    const int am = tid & 31;              // A staging row
    const int ak = tid >> 5;              // A staging k-chunk 0..7

    float acc[4][4] = {};

    for (int k0 = k_beg; k0 < k_end; k0 += BK) {
        // A tile 32x32 -> k-major LDS (1 float4 per thread)
        float4 av = *(const float4*)(A + (size_t)am * DIM + k0 + ak * 4);
        As[ak * 4 + 0][am] = av.x;
        As[ak * 4 + 1][am] = av.y;
        As[ak * 4 + 2][am] = av.z;
        As[ak * 4 + 3][am] = av.w;
        // B tile 32x128 (4 float4 per thread)
        #pragma unroll
        for (int i = 0; i < 4; i++) {
            int idx = tid + i * 256;
            int r = idx >> 5, c = (idx & 31) * 4;
            *(float4*)&Bs[r][c] = *(const float4*)(W + (size_t)(k0 + r) * DIM + n0 + c);
        }
        __syncthreads();
        #pragma unroll
        for (int kk = 0; kk < BK; kk++) {
            float4 a4 = *(const float4*)&As[kk][my * 4];
            float4 b4 = *(const float4*)&Bs[kk][nx * 4];
            const float* ap = (const float*)&a4;
            const float* bp = (const float*)&b4;
            #pragma unroll
            for (int j = 0; j < 4; j++)
                #pragma unroll
                for (int i = 0; i < 4; i++)
                    acc[j][i] += ap[j] * bp[i];
        }
        __syncthreads();
    }
    #pragma unroll
    for (int j = 0; j < 4; j++) {
        float4 o = {acc[j][0], acc[j][1], acc[j][2], acc[j][3]};
        *(float4*)(Cp + ((size_t)kz * MROWS + t * BM + my * 4 + j) * DIM + n0 + nx * 4) = o;
    }
}

// ---------------- K2: reduce partials + e[s,b] = v . tanh(enc+dec+b) ----------------
template <int P>
__global__ __launch_bounds__(128) void k_energy(
    const float* __restrict__ Cp,
    const unsigned char* __restrict__ mask,   // (S,B) bool
    const float* __restrict__ bias,
    const float* __restrict__ v,
    float* __restrict__ e)                    // 288
{
    const int r = blockIdx.x;                 // 0..287 (= s*32+b)
    const int b = r & 31;
    const int lane = threadIdx.x & 63;
    const int w = threadIdx.x >> 6;
    const float* encB = Cp + (size_t)(32 + r) * DIM;
    const float* decB = Cp + (size_t)b * DIM;
    float sum = 0.f;
    #pragma unroll
    for (int it = 0; it < 2; it++) {
        int h = w * 512 + it * 256 + lane * 4;
        float4 x = *(const float4*)(bias + h);
        #pragma unroll
        for (int p = 0; p < P; p++) {
            float4 ev4 = *(const float4*)(encB + (size_t)p * MROWS * DIM + h);
            float4 dv4 = *(const float4*)(decB + (size_t)p * MROWS * DIM + h);
            x.x += ev4.x + dv4.x;
            x.y += ev4.y + dv4.y;
            x.z += ev4.z + dv4.z;
            x.w += ev4.w + dv4.w;
        }
        float4 vv = *(const float4*)(v + h);
        sum += vv.x * fast_tanh(x.x) + vv.y * fast_tanh(x.y)
             + vv.z * fast_tanh(x.z) + vv.w * fast_tanh(x.w);
    }
    #pragma unroll
    for (int off = 32; off; off >>= 1) sum += __shfl_down(sum, off);
    __shared__ float part[2];
    if (lane == 0) part[w] = sum;
    __syncthreads();
    if (threadIdx.x == 0) {
        float s2 = part[0] + part[1];
        int s = r >> 5;
        if (mask[(size_t)s * B_SZ + b]) s2 = NEGINF;
        e[r] = s2;
    }
}

// ---------------- K3: softmax(9) + weighted context + alpha one-hot ----------------
__global__ __launch_bounds__(64) void k_context(
    const float* __restrict__ e,
    const float* __restrict__ src,
    float* __restrict__ out,                  // 32 x 1024
    float* __restrict__ alpha)                // 2048 x 32
{
    const int b = blockIdx.x;                 // 0..31
    const int q = blockIdx.y;                 // 0..3
    const int tid = threadIdx.x;
    // alpha: 65536 floats = 16384 float4 over 8192 threads -> 2 each
    const int bid = q * 32 + b;
    #pragma unroll
    for (int i = 0; i < 2; i++) {
        int c4 = bid * 64 + tid + i * 8192;
        float val = (c4 >= 64 && c4 < 72) ? 1.f : 0.f;   // floats 256..287 = row 8
        float4 o = {val, val, val, val};
        *(float4*)(alpha + (size_t)c4 * 4) = o;
    }
    float ev[PTR];
    float m = -INFINITY;
    #pragma unroll
    for (int s = 0; s < PTR; s++) { ev[s] = e[s * B_SZ + b]; m = fmaxf(m, ev[s]); }
    float sum = 0.f;
    #pragma unroll
    for (int s = 0; s < PTR; s++) { ev[s] = __expf(ev[s] - m) + EPSV; sum += ev[s]; }
    float inv = __builtin_amdgcn_rcpf(sum);
    const int h = q * 256 + tid * 4;
    float4 acc = {0.f, 0.f, 0.f, 0.f};
    #pragma unroll
    for (int s = 0; s < PTR; s++) {
        float wgt = ev[s] * inv;
        float4 x = *(const float4*)(src + (size_t)(s * B_SZ + b) * DIM + h);
        acc.x += wgt * x.x; acc.y += wgt * x.y; acc.z += wgt * x.z; acc.w += wgt * x.w;
    }
    *(float4*)(out + (size_t)b * DIM + h) = acc;
}

extern "C" void kernel_launch(void* const* d_in, const int* in_sizes, int n_in,
                              void* d_out, int out_size, void* d_ws, size_t ws_size,
                              hipStream_t stream) {
    const float* input = (const float*)d_in[0];
    const float* src   = (const float*)d_in[1];
    const unsigned char* mask = (const unsigned char*)d_in[2];
    const float* Wdec  = (const float*)d_in[3];
    const float* Wenc  = (const float*)d_in[4];
    const float* bias  = (const float*)d_in[5];
    const float* v     = (const float*)d_in[6];
    float* out   = (float*)d_out;
    float* alpha = out + B_SZ * DIM;

    int P = 8;
    while (P > 1 && ((size_t)P * MROWS * DIM * 4 + 4096) > ws_size) P >>= 1;
    float* Cp = (float*)d_ws;
    float* e  = Cp + (size_t)P * MROWS * DIM;
    int Kslice = DIM / P;

    k_gemm<<<dim3(DIM / BN, 10, P), 256, 0, stream>>>(input, src, Wdec, Wenc, Cp, Kslice);
    switch (P) {
        case 8: k_energy<8><<<dim3(288), 128, 0, stream>>>(Cp, mask, bias, v, e); break;
        case 4: k_energy<4><<<dim3(288), 128, 0, stream>>>(Cp, mask, bias, v, e); break;
        case 2: k_energy<2><<<dim3(288), 128, 0, stream>>>(Cp, mask, bias, v, e); break;
        default: k_energy<1><<<dim3(288), 128, 0, stream>>>(Cp, mask, bias, v, e); break;
    }
    k_context<<<dim3(B_SZ, 4), 64, 0, stream>>>(e, src, out, alpha);
}

// Round 3
// 29.582 us; speedup vs baseline: 1.6225x; 1.0060x over previous
//
#include <hip/hip_runtime.h>
#include <hip/hip_bf16.h>
#include <math.h>

#define S_LEN 2048
#define B_SZ  32
#define DIM   1024   // D == E == H == 1024
#define PTR   9      // min((0 + 9) * 1, 2047)
#define EPSV  1e-8f
#define NEGINF -1e9f
#define MROWS 320    // 32 dec rows + 288 enc rows

typedef __attribute__((ext_vector_type(8)))  short  short8;
typedef __attribute__((ext_vector_type(16))) float  f32x16;

__device__ __forceinline__ ushort f2bf(float x) {
    __hip_bfloat16 h = __float2bfloat16(x);   // RNE
    return *(ushort*)&h;
}

__device__ __forceinline__ float fast_tanh(float x) {
    float xc = fminf(fmaxf(x, -20.f), 20.f);
    float t = __expf(2.f * xc);
    return (t - 1.f) * __builtin_amdgcn_rcpf(t + 1.f);
}

// ---------------- K0: cast A rows (input ++ first 9 s-rows of src) to bf16 ----------------
__global__ __launch_bounds__(256) void k_cvtA(
    const float* __restrict__ input,
    const float* __restrict__ src,
    ushort* __restrict__ Abf)
{
    int base = (blockIdx.x * 256 + threadIdx.x) * 4;       // 320*1024 elems
    const float* p = (base < 32 * DIM) ? (input + base) : (src + (size_t)(base - 32 * DIM));
    float4 x = *(const float4*)p;
    ushort4 o = {f2bf(x.x), f2bf(x.y), f2bf(x.z), f2bf(x.w)};
    *(ushort4*)(Abf + base) = o;
}

// ---------------- K1: transpose+cast W [K][N] f32 -> BT [N][K] bf16 ----------------
__global__ __launch_bounds__(256) void k_cvtT(
    const float* __restrict__ Wd, const float* __restrict__ We,
    ushort* __restrict__ BTd, ushort* __restrict__ BTe)
{
    __shared__ float t[64][65];
    const float* W  = blockIdx.z ? We : Wd;
    ushort* BT      = blockIdx.z ? BTe : BTd;
    const int k0 = blockIdx.y * 64, n0 = blockIdx.x * 64;
    const int tid = threadIdx.x;
    #pragma unroll
    for (int i = 0; i < 4; i++) {
        int idx = tid + i * 256;                 // 1024 float4 chunks
        int r = idx >> 4, c4 = (idx & 15) * 4;   // r = k-row, c4 = n-col
        float4 x = *(const float4*)(W + (size_t)(k0 + r) * DIM + n0 + c4);
        t[r][c4] = x.x; t[r][c4 + 1] = x.y; t[r][c4 + 2] = x.z; t[r][c4 + 3] = x.w;
    }
    __syncthreads();
    #pragma unroll
    for (int i = 0; i < 4; i++) {
        int idx = tid + i * 256;
        int n = idx >> 4, kc = (idx & 15) * 4;
        ushort4 o = {f2bf(t[kc][n]), f2bf(t[kc + 1][n]), f2bf(t[kc + 2][n]), f2bf(t[kc + 3][n])};
        *(ushort4*)(BT + (size_t)(n0 + n) * DIM + k0 + kc) = o;
    }
}

// ---------------- K2: MFMA GEMM, one wave per 32x32 output tile ----------------
// C rows 0..31 = input@Wdec (no bias), rows 32+r = srcrow r @ Wenc
__global__ __launch_bounds__(64) void k_gemm(
    const ushort* __restrict__ Abf,
    const ushort* __restrict__ BTd,
    const ushort* __restrict__ BTe,
    float* __restrict__ C)
{
    const int nt = blockIdx.x;                   // 0..31
    const int mt = blockIdx.y;                   // 0..9 (0 = dec tile)
    const ushort* BT = (mt == 0) ? BTd : BTe;
    const int lane = threadIdx.x;
    const int r32  = lane & 31;
    const int kh   = lane >> 5;                  // k-half: elems kh*8..kh*8+7
    const ushort* Ap = Abf + (size_t)(mt * 32 + r32) * DIM + kh * 8;
    const ushort* Bp = BT  + (size_t)(nt * 32 + r32) * DIM + kh * 8;

    f32x16 acc;
    #pragma unroll
    for (int i = 0; i < 16; i++) acc[i] = 0.f;

    #pragma unroll 8
    for (int k = 0; k < DIM; k += 16) {
        short8 a = *(const short8*)(Ap + k);
        short8 b = *(const short8*)(Bp + k);
        acc = __builtin_amdgcn_mfma_f32_32x32x16_bf16(a, b, acc, 0, 0, 0);
    }
    // C/D layout: col = lane&31, row = (reg&3) + 8*(reg>>2) + 4*(lane>>5)
    #pragma unroll
    for (int r = 0; r < 16; r++) {
        int m = (r & 3) + 8 * (r >> 2) + 4 * kh;
        C[(size_t)(mt * 32 + m) * DIM + nt * 32 + r32] = acc[r];
    }
}

// ---------------- K3: e[s,b] = v . tanh(enc + dec + bias), mask -> -1e9 ----------------
__global__ __launch_bounds__(256) void k_energy(
    const float* __restrict__ C,
    const unsigned char* __restrict__ mask,
    const float* __restrict__ bias,
    const float* __restrict__ v,
    float* __restrict__ e)                    // 288
{
    const int r = blockIdx.x;                 // 0..287 (= s*32+b)
    const int b = r & 31;
    const int lane = threadIdx.x & 63;
    const int w = threadIdx.x >> 6;
    const int h = threadIdx.x * 4;
    float4 ev4 = *(const float4*)(C + (size_t)(32 + r) * DIM + h);
    float4 dv4 = *(const float4*)(C + (size_t)b * DIM + h);
    float4 bb  = *(const float4*)(bias + h);
    float4 vv  = *(const float4*)(v + h);
    float sum = vv.x * fast_tanh(ev4.x + dv4.x + bb.x)
              + vv.y * fast_tanh(ev4.y + dv4.y + bb.y)
              + vv.z * fast_tanh(ev4.z + dv4.z + bb.z)
              + vv.w * fast_tanh(ev4.w + dv4.w + bb.w);
    #pragma unroll
    for (int off = 32; off; off >>= 1) sum += __shfl_down(sum, off);
    __shared__ float part[4];
    if (lane == 0) part[w] = sum;
    __syncthreads();
    if (threadIdx.x == 0) {
        float s2 = part[0] + part[1] + part[2] + part[3];
        int s = r >> 5;
        if (mask[(size_t)s * B_SZ + b]) s2 = NEGINF;
        e[r] = s2;
    }
}

// ---------------- K4: softmax(9) + weighted context + alpha one-hot ----------------
__global__ __launch_bounds__(64) void k_context(
    const float* __restrict__ e,
    const float* __restrict__ src,
    float* __restrict__ out,                  // 32 x 1024
    float* __restrict__ alpha)                // 2048 x 32
{
    const int b = blockIdx.x;                 // 0..31
    const int q = blockIdx.y;                 // 0..3
    const int tid = threadIdx.x;
    const int bid = q * 32 + b;
    #pragma unroll
    for (int i = 0; i < 2; i++) {
        int c4 = bid * 64 + tid + i * 8192;
        float val = (c4 >= 64 && c4 < 72) ? 1.f : 0.f;   // floats 256..287 = row 8
        float4 o = {val, val, val, val};
        *(float4*)(alpha + (size_t)c4 * 4) = o;
    }
    float ev[PTR];
    float m = -INFINITY;
    #pragma unroll
    for (int s = 0; s < PTR; s++) { ev[s] = e[s * B_SZ + b]; m = fmaxf(m, ev[s]); }
    float sum = 0.f;
    #pragma unroll
    for (int s = 0; s < PTR; s++) { ev[s] = __expf(ev[s] - m) + EPSV; sum += ev[s]; }
    float inv = __builtin_amdgcn_rcpf(sum);
    const int h = q * 256 + tid * 4;
    float4 acc = {0.f, 0.f, 0.f, 0.f};
    #pragma unroll
    for (int s = 0; s < PTR; s++) {
        float wgt = ev[s] * inv;
        float4 x = *(const float4*)(src + (size_t)(s * B_SZ + b) * DIM + h);
        acc.x += wgt * x.x; acc.y += wgt * x.y; acc.z += wgt * x.z; acc.w += wgt * x.w;
    }
    *(float4*)(out + (size_t)b * DIM + h) = acc;
}

extern "C" void kernel_launch(void* const* d_in, const int* in_sizes, int n_in,
                              void* d_out, int out_size, void* d_ws, size_t ws_size,
                              hipStream_t stream) {
    const float* input = (const float*)d_in[0];
    const float* src   = (const float*)d_in[1];
    const unsigned char* mask = (const unsigned char*)d_in[2];
    const float* Wdec  = (const float*)d_in[3];
    const float* Wenc  = (const float*)d_in[4];
    const float* bias  = (const float*)d_in[5];
    const float* v     = (const float*)d_in[6];
    float* out   = (float*)d_out;
    float* alpha = out + B_SZ * DIM;

    ushort* Abf = (ushort*)d_ws;                       // 320*1024 bf16
    ushort* BTd = Abf + (size_t)MROWS * DIM;           // 1024*1024 bf16
    ushort* BTe = BTd + (size_t)DIM * DIM;             // 1024*1024 bf16
    float*  C   = (float*)(BTe + (size_t)DIM * DIM);   // 320*1024 f32
    float*  e   = C + (size_t)MROWS * DIM;             // 288 f32

    k_cvtA<<<dim3(MROWS * DIM / 1024), 256, 0, stream>>>(input, src, Abf);
    k_cvtT<<<dim3(16, 16, 2), 256, 0, stream>>>(Wdec, Wenc, BTd, BTe);
    k_gemm<<<dim3(32, 10), 64, 0, stream>>>(Abf, BTd, BTe, C);
    k_energy<<<dim3(288), 256, 0, stream>>>(C, mask, bias, v, e);
    k_context<<<dim3(B_SZ, 4), 64, 0, stream>>>(e, src, out, alpha);
}